// Round 6
// baseline (1390.936 us; speedup 1.0000x reference)
//
#include <hip/hip_runtime.h>
#include <hip/hip_bf16.h>
#include <math.h>

#define BATCH 256
#define SEQ   512
#define INS   300
#define KP    320   // K padded to 10 x 32 (xg gemm)
#define HID   128
#define NG    384   // 3*HID

typedef __attribute__((ext_vector_type(8))) short short8;   // 8 x bf16 (4 VGPRs)
typedef __attribute__((ext_vector_type(4))) float f32x4;

// ---------- helpers ----------
__device__ __forceinline__ float bf2f(unsigned short u) {
    unsigned int v = ((unsigned int)u) << 16;
    return __uint_as_float(v);
}
__device__ __forceinline__ unsigned short f2bf(float f) {
    unsigned int u = __float_as_uint(f);
    unsigned int r = (u + 0x7FFFu + ((u >> 16) & 1u)) >> 16;
    return (unsigned short)r;
}

// ---------- Kernel 0: split W_ih (fp32 384x300) -> bf16 hi/lo planes (384x320, k-padded) ----------
__global__ void conv_wih(const float* __restrict__ Wih,
                         unsigned short* __restrict__ Whi,
                         unsigned short* __restrict__ Wlo)
{
    int idx = blockIdx.x * 256 + threadIdx.x;     // 0 .. 384*320-1
    if (idx >= NG * KP) return;
    int g = idx / KP, k = idx - g * KP;
    float v = (k < INS) ? Wih[g * INS + k] : 0.f;
    unsigned short h = f2bf(v);
    float r = v - bf2f(h);
    Whi[idx] = h;
    Wlo[idx] = f2bf(r);
}

// ---------- Kernel A: xg = x @ W_ih^T + b_ih via split-bf16 MFMA (unchanged) ----------
template <bool BF16OUT>
__launch_bounds__(256)
__global__ void xg_mfma(const float* __restrict__ x,
                        const unsigned short* __restrict__ Whi,
                        const unsigned short* __restrict__ Wlo,
                        const float* __restrict__ bih,
                        void* __restrict__ xg_out,
                        int t0, int CT)
{
    __shared__ unsigned short Ah[128][40], Al[128][40];
    __shared__ unsigned short Bh[128][40], Bl[128][40];

    const int tid  = threadIdx.x;
    const int lane = tid & 63;
    const int w    = tid >> 6;
    const int wm   = (w & 1) * 64;
    const int wn   = (w >> 1) * 64;
    const int n0   = blockIdx.x * 128;
    const int m0   = blockIdx.y * 128;

    const int srow = tid >> 1;
    const int shalf = tid & 1;
    const int rr = m0 + srow;
    const int bb = rr / CT;
    const float* xrow = x + (size_t)(bb * SEQ + t0 + (rr - bb * CT)) * INS;

    f32x4 acc[4][4] = {};

    for (int ks = 0; ks < KP / 32; ks++) {
        const int k0 = ks * 32 + shalf * 16;
        float v[16];
        #pragma unroll
        for (int i = 0; i < 16; i += 4) {
            if (k0 + i + 4 <= INS) {
                float4 f = *(const float4*)(xrow + k0 + i);
                v[i] = f.x; v[i + 1] = f.y; v[i + 2] = f.z; v[i + 3] = f.w;
            } else {
                #pragma unroll
                for (int j = 0; j < 4; j++)
                    v[i + j] = (k0 + i + j < INS) ? xrow[k0 + i + j] : 0.f;
            }
        }
        union { unsigned short us[8]; uint4 q; } ph, pl;
        #pragma unroll
        for (int gblk = 0; gblk < 2; gblk++) {
            #pragma unroll
            for (int i = 0; i < 8; i++) {
                float f = v[gblk * 8 + i];
                unsigned short h = f2bf(f);
                ph.us[i] = h;
                pl.us[i] = f2bf(f - bf2f(h));
            }
            *(uint4*)&Ah[srow][shalf * 16 + gblk * 8] = ph.q;
            *(uint4*)&Al[srow][shalf * 16 + gblk * 8] = pl.q;
        }
        {
            const size_t off = (size_t)(n0 + srow) * KP + ks * 32 + shalf * 16;
            const uint4* sh = (const uint4*)(Whi + off);
            const uint4* sl = (const uint4*)(Wlo + off);
            *(uint4*)&Bh[srow][shalf * 16]     = sh[0];
            *(uint4*)&Bh[srow][shalf * 16 + 8] = sh[1];
            *(uint4*)&Bl[srow][shalf * 16]     = sl[0];
            *(uint4*)&Bl[srow][shalf * 16 + 8] = sl[1];
        }
        __syncthreads();

        const int lm = lane & 15;
        const int lk = (lane >> 4) * 8;
        short8 ah[4], al[4], bh[4], bl[4];
        #pragma unroll
        for (int mi = 0; mi < 4; mi++) {
            ah[mi] = *(const short8*)&Ah[wm + mi * 16 + lm][lk];
            al[mi] = *(const short8*)&Al[wm + mi * 16 + lm][lk];
        }
        #pragma unroll
        for (int ni = 0; ni < 4; ni++) {
            bh[ni] = *(const short8*)&Bh[wn + ni * 16 + lm][lk];
            bl[ni] = *(const short8*)&Bl[wn + ni * 16 + lm][lk];
        }
        #pragma unroll
        for (int mi = 0; mi < 4; mi++) {
            #pragma unroll
            for (int ni = 0; ni < 4; ni++) {
                acc[mi][ni] = __builtin_amdgcn_mfma_f32_16x16x32_bf16(ah[mi], bh[ni], acc[mi][ni], 0, 0, 0);
                acc[mi][ni] = __builtin_amdgcn_mfma_f32_16x16x32_bf16(ah[mi], bl[ni], acc[mi][ni], 0, 0, 0);
                acc[mi][ni] = __builtin_amdgcn_mfma_f32_16x16x32_bf16(al[mi], bh[ni], acc[mi][ni], 0, 0, 0);
            }
        }
        __syncthreads();
    }

    const int crow = wm + ((lane >> 4) * 4);
    const int ccol = wn + (lane & 15);
    #pragma unroll
    for (int ni = 0; ni < 4; ni++) {
        const int col = n0 + ccol + ni * 16;
        const float bias = bih[col];
        #pragma unroll
        for (int mi = 0; mi < 4; mi++) {
            #pragma unroll
            for (int i = 0; i < 4; i++) {
                const size_t row = (size_t)(m0 + crow + mi * 16 + i);
                const float val = acc[mi][ni][i] + bias;
                if (BF16OUT) ((unsigned short*)xg_out)[row * NG + col] = f2bf(val);
                else         ((float*)xg_out)[row * NG + col] = val;
            }
        }
    }
}

// ---------- Kernel B: MFMA recurrence, 16 batch rows per block ----------
// grid = 16 blocks x 512 threads (8 waves, 2/SIMD). A = 16 h rows (bf16, LDS,
// double-buffered), B = W_hh^T persistent in VGPRs as 2-split (W=hi+lo exact;
// h plain bf16 -> per-step hg error ~7e-4). Per SIMD per step: 48 MFMAs
// x 16cyc = 768 cyc pipe (vs 1152+ before, zero M-waste). Wave wv owns gate
// cols [16wv,16wv+16) for all 3 gates; each lane does 4 h-updates (all 64
// lanes active). One raw lgkmcnt-barrier per step; xg prefetch crosses it.
template <bool BF16XG>
__launch_bounds__(512, 2)
__global__ void gru_mfma(const void* __restrict__ xg_in,
                         const float* __restrict__ Whh,
                         const float* __restrict__ bhh,
                         float* __restrict__ hstate,
                         int t0, int CT, int initial, int final_chunk,
                         const float* __restrict__ Wout,
                         const float* __restrict__ bout,
                         float* __restrict__ out)
{
    const int tid  = threadIdx.x;
    const int wv   = tid >> 6;      // 0..7
    const int lane = tid & 63;
    const int lm   = lane & 15;
    const int quad = lane >> 4;
    const int R0   = blockIdx.x * 16;    // this block's batch rows [R0, R0+16)
    const int j    = wv * 16 + lm;       // this lane's gate column (0..127)

    __shared__ alignas(16) unsigned short h_s[2][16][136];  // bf16 h, padded row
    __shared__ alignas(16) float hf[16][132];               // final h (head)

    // ---- persistent B fragments: B[k=kt*32+quad*8+i][n=tile] = Whh[n][k] ----
    // wave wv's N-tiles: r: gates [16wv,16wv+16), z: +128, n: +256
    short8 w_hi[3][4], w_lo[3][4];
    #pragma unroll
    for (int t = 0; t < 3; t++) {
        const float* wr = Whh + (size_t)(t * 128 + j) * HID + quad * 8;
        #pragma unroll
        for (int kt = 0; kt < 4; kt++) {
            float4 f0 = *(const float4*)(wr + kt * 32);
            float4 f1 = *(const float4*)(wr + kt * 32 + 4);
            float vv[8] = {f0.x, f0.y, f0.z, f0.w, f1.x, f1.y, f1.z, f1.w};
            short8 h8, l8;
            #pragma unroll
            for (int i = 0; i < 8; i++) {
                unsigned short h = f2bf(vv[i]);
                h8[i] = (short)h;
                l8[i] = (short)f2bf(vv[i] - bf2f(h));
            }
            w_hi[t][kt] = h8;
            w_lo[t][kt] = l8;
        }
    }

    const float bhr = bhh[j], bhz = bhh[HID + j], bhn = bhh[2 * HID + j];

    // ---- per-lane h state: rows m_i = quad*4 + i, column j ----
    float hp[4];
    #pragma unroll
    for (int i = 0; i < 4; i++) {
        const int m = quad * 4 + i;
        hp[i] = initial ? 0.f : hstate[(size_t)(R0 + m) * HID + j];
        h_s[0][m][j] = f2bf(hp[i]);
    }

    // ---- prefetch xg for step 0 ----
    const float* xgf = (const float*)xg_in;
    const unsigned short* xgb = (const unsigned short*)xg_in;
    float nxr[4], nxz[4], nxn[4];
    #pragma unroll
    for (int i = 0; i < 4; i++) {
        const size_t nb = ((size_t)(R0 + quad * 4 + i) * CT) * NG + j;
        if (BF16XG) { nxr[i] = bf2f(xgb[nb]); nxz[i] = bf2f(xgb[nb + HID]); nxn[i] = bf2f(xgb[nb + 2 * HID]); }
        else        { nxr[i] = xgf[nb];       nxz[i] = xgf[nb + HID];       nxn[i] = xgf[nb + 2 * HID]; }
    }
    __syncthreads();

    for (int tt = 0; tt < CT; tt++) {
        const int p = tt & 1;
        // ---- A fragments: A[m=lm][k=kt*32+quad*8+i] = h[m][k] ----
        short8 a[4];
        #pragma unroll
        for (int kt = 0; kt < 4; kt++)
            a[kt] = *(const short8*)&h_s[p][lm][kt * 32 + quad * 8];

        // ---- hg tiles: (W_hi + W_lo) x h_bf16, shared accumulator ----
        f32x4 acc[3] = {};
        #pragma unroll
        for (int kt = 0; kt < 4; kt++) {
            #pragma unroll
            for (int t = 0; t < 3; t++)
                acc[t] = __builtin_amdgcn_mfma_f32_16x16x32_bf16(a[kt], w_hi[t][kt], acc[t], 0, 0, 0);
            #pragma unroll
            for (int t = 0; t < 3; t++)
                acc[t] = __builtin_amdgcn_mfma_f32_16x16x32_bf16(a[kt], w_lo[t][kt], acc[t], 0, 0, 0);
        }

        // ---- activation: lane owns (m = quad*4+i, j); D row=(lane>>4)*4+reg ----
        #pragma unroll
        for (int i = 0; i < 4; i++) {
            const int m = quad * 4 + i;
            float hgr = acc[0][i] + bhr;
            float hgz = acc[1][i] + bhz;
            float hgn = acc[2][i] + bhn;
            float rg = 1.f / (1.f + __expf(-(nxr[i] + hgr)));
            float zg = 1.f / (1.f + __expf(-(nxz[i] + hgz)));
            float nv = nxn[i] + rg * hgn;
            float e  = __expf(2.f * nv);
            float ng = 1.f - 2.f / (e + 1.f);   // tanh, saturates at +/-inf
            hp[i] = (1.f - zg) * ng + zg * hp[i];
            h_s[1 - p][m][j] = f2bf(hp[i]);
            if (tt + 1 < CT) {   // prefetch next xg; stays in flight across barrier
                const size_t nb = ((size_t)(R0 + m) * CT + tt + 1) * NG + j;
                if (BF16XG) { nxr[i] = bf2f(xgb[nb]); nxz[i] = bf2f(xgb[nb + HID]); nxn[i] = bf2f(xgb[nb + 2 * HID]); }
                else        { nxr[i] = xgf[nb];       nxz[i] = xgf[nb + HID];       nxn[i] = xgf[nb + 2 * HID]; }
            }
        }
        // drain LDS writes only (not vmcnt), then barrier
        asm volatile("s_waitcnt lgkmcnt(0)\ns_barrier" ::: "memory");
    }

    if (!final_chunk) {
        #pragma unroll
        for (int i = 0; i < 4; i++)
            hstate[(size_t)(R0 + quad * 4 + i) * HID + j] = hp[i];
        return;
    }

    // ---- head: relu -> 2-class linear -> log_softmax (wave wv: rows 2wv,2wv+1) ----
    #pragma unroll
    for (int i = 0; i < 4; i++)
        hf[quad * 4 + i][j] = hp[i];
    __syncthreads();

    #pragma unroll
    for (int rr = 0; rr < 2; rr++) {
        const int row = 2 * wv + rr;
        float f0 = hf[row][lane];       f0 = f0 > 0.f ? f0 : 0.f;
        float f1 = hf[row][lane + 64];  f1 = f1 > 0.f ? f1 : 0.f;
        float l0 = f0 * Wout[lane] + f1 * Wout[lane + 64];
        float l1 = f0 * Wout[HID + lane] + f1 * Wout[HID + lane + 64];
        #pragma unroll
        for (int d = 32; d > 0; d >>= 1) {
            l0 += __shfl_down(l0, d, 64);
            l1 += __shfl_down(l1, d, 64);
        }
        if (lane == 0) {
            l0 += bout[0]; l1 += bout[1];
            float m = fmaxf(l0, l1);
            float lse = m + logf(__expf(l0 - m) + __expf(l1 - m));
            out[(R0 + row) * 2 + 0] = l0 - lse;
            out[(R0 + row) * 2 + 1] = l1 - lse;
        }
    }
}

// ---------- launch ----------
extern "C" void kernel_launch(void* const* d_in, const int* in_sizes, int n_in,
                              void* d_out, int out_size, void* d_ws, size_t ws_size,
                              hipStream_t stream) {
    const float* x    = (const float*)d_in[0];
    const float* Wih  = (const float*)d_in[1];
    const float* Whh  = (const float*)d_in[2];
    const float* bih  = (const float*)d_in[3];
    const float* bhh  = (const float*)d_in[4];
    const float* Wout = (const float*)d_in[5];
    const float* bout = (const float*)d_in[6];
    float* out = (float*)d_out;

    // ws layout: [W_hi | W_lo | hstate | xg]
    unsigned short* Whi = (unsigned short*)d_ws;                       // 384*320*2 = 245760 B
    unsigned short* Wlo = (unsigned short*)((char*)d_ws + 245760);
    float* hstate = (float*)((char*)d_ws + 491520);                    // 128 KiB
    void*  xg     = (void*)((char*)d_ws + 622592);
    const size_t avail = ws_size > 622592 ? ws_size - 622592 : 0;

    bool bf16;
    int CT;
    if (avail >= (size_t)BATCH * SEQ * NG * 4) {        // fp32 xg (201 MB)
        bf16 = false; CT = SEQ;
    } else if (avail >= (size_t)BATCH * SEQ * NG * 2) { // bf16 xg (100 MB)
        bf16 = true;  CT = SEQ;
    } else {                                            // chunked bf16
        bf16 = true;
        CT = 64;
        while (CT * 2 <= SEQ && avail >= (size_t)BATCH * (size_t)(CT * 2) * NG * 2) CT *= 2;
    }

    conv_wih<<<(NG * KP + 255) / 256, 256, 0, stream>>>(Wih, Whi, Wlo);

    for (int t0 = 0; t0 < SEQ; t0 += CT) {
        dim3 gridA(NG / 128, (BATCH * CT) / 128);
        const int initial = (t0 == 0);
        const int final_chunk = (t0 + CT >= SEQ);
        if (bf16) {
            xg_mfma<true><<<gridA, 256, 0, stream>>>(x, Whi, Wlo, bih, xg, t0, CT);
            gru_mfma<true><<<16, 512, 0, stream>>>(xg, Whh, bhh, hstate, t0, CT,
                                                   initial, final_chunk, Wout, bout, out);
        } else {
            xg_mfma<false><<<gridA, 256, 0, stream>>>(x, Whi, Wlo, bih, xg, t0, CT);
            gru_mfma<false><<<16, 512, 0, stream>>>(xg, Whh, bhh, hstate, t0, CT,
                                                    initial, final_chunk, Wout, bout, out);
        }
    }
}

// Round 7
// 1132.056 us; speedup vs baseline: 1.2287x; 1.2287x over previous
//
#include <hip/hip_runtime.h>
#include <hip/hip_bf16.h>
#include <math.h>

#define BATCH 256
#define SEQ   512
#define INS   300
#define KP    320   // K padded to 10 x 32 (xg gemm)
#define HID   128
#define NG    384   // 3*HID
#define RPB   4     // batch rows per gru block

typedef __attribute__((ext_vector_type(8))) short short8;   // 8 x bf16 (4 VGPRs)
typedef __attribute__((ext_vector_type(4))) float f32x4;

// ---------- helpers ----------
__device__ __forceinline__ float bf2f(unsigned short u) {
    unsigned int v = ((unsigned int)u) << 16;
    return __uint_as_float(v);
}
__device__ __forceinline__ unsigned short f2bf(float f) {
    unsigned int u = __float_as_uint(f);
    unsigned int r = (u + 0x7FFFu + ((u >> 16) & 1u)) >> 16;
    return (unsigned short)r;
}

// ---------- Kernel 0: split W_ih (fp32 384x300) -> bf16 hi/lo planes (384x320, k-padded) ----------
__global__ void conv_wih(const float* __restrict__ Wih,
                         unsigned short* __restrict__ Whi,
                         unsigned short* __restrict__ Wlo)
{
    int idx = blockIdx.x * 256 + threadIdx.x;     // 0 .. 384*320-1
    if (idx >= NG * KP) return;
    int g = idx / KP, k = idx - g * KP;
    float v = (k < INS) ? Wih[g * INS + k] : 0.f;
    unsigned short h = f2bf(v);
    float r = v - bf2f(h);
    Whi[idx] = h;
    Wlo[idx] = f2bf(r);
}

// ---------- Kernel A: xg = x @ W_ih^T + b_ih via split-bf16 MFMA (unchanged) ----------
template <bool BF16OUT>
__launch_bounds__(256)
__global__ void xg_mfma(const float* __restrict__ x,
                        const unsigned short* __restrict__ Whi,
                        const unsigned short* __restrict__ Wlo,
                        const float* __restrict__ bih,
                        void* __restrict__ xg_out,
                        int t0, int CT)
{
    __shared__ unsigned short Ah[128][40], Al[128][40];
    __shared__ unsigned short Bh[128][40], Bl[128][40];

    const int tid  = threadIdx.x;
    const int lane = tid & 63;
    const int w    = tid >> 6;
    const int wm   = (w & 1) * 64;
    const int wn   = (w >> 1) * 64;
    const int n0   = blockIdx.x * 128;
    const int m0   = blockIdx.y * 128;

    const int srow = tid >> 1;
    const int shalf = tid & 1;
    const int rr = m0 + srow;
    const int bb = rr / CT;
    const float* xrow = x + (size_t)(bb * SEQ + t0 + (rr - bb * CT)) * INS;

    f32x4 acc[4][4] = {};

    for (int ks = 0; ks < KP / 32; ks++) {
        const int k0 = ks * 32 + shalf * 16;
        float v[16];
        #pragma unroll
        for (int i = 0; i < 16; i += 4) {
            if (k0 + i + 4 <= INS) {
                float4 f = *(const float4*)(xrow + k0 + i);
                v[i] = f.x; v[i + 1] = f.y; v[i + 2] = f.z; v[i + 3] = f.w;
            } else {
                #pragma unroll
                for (int j = 0; j < 4; j++)
                    v[i + j] = (k0 + i + j < INS) ? xrow[k0 + i + j] : 0.f;
            }
        }
        union { unsigned short us[8]; uint4 q; } ph, pl;
        #pragma unroll
        for (int gblk = 0; gblk < 2; gblk++) {
            #pragma unroll
            for (int i = 0; i < 8; i++) {
                float f = v[gblk * 8 + i];
                unsigned short h = f2bf(f);
                ph.us[i] = h;
                pl.us[i] = f2bf(f - bf2f(h));
            }
            *(uint4*)&Ah[srow][shalf * 16 + gblk * 8] = ph.q;
            *(uint4*)&Al[srow][shalf * 16 + gblk * 8] = pl.q;
        }
        {
            const size_t off = (size_t)(n0 + srow) * KP + ks * 32 + shalf * 16;
            const uint4* sh = (const uint4*)(Whi + off);
            const uint4* sl = (const uint4*)(Wlo + off);
            *(uint4*)&Bh[srow][shalf * 16]     = sh[0];
            *(uint4*)&Bh[srow][shalf * 16 + 8] = sh[1];
            *(uint4*)&Bl[srow][shalf * 16]     = sl[0];
            *(uint4*)&Bl[srow][shalf * 16 + 8] = sl[1];
        }
        __syncthreads();

        const int lm = lane & 15;
        const int lk = (lane >> 4) * 8;
        short8 ah[4], al[4], bh[4], bl[4];
        #pragma unroll
        for (int mi = 0; mi < 4; mi++) {
            ah[mi] = *(const short8*)&Ah[wm + mi * 16 + lm][lk];
            al[mi] = *(const short8*)&Al[wm + mi * 16 + lm][lk];
        }
        #pragma unroll
        for (int ni = 0; ni < 4; ni++) {
            bh[ni] = *(const short8*)&Bh[wn + ni * 16 + lm][lk];
            bl[ni] = *(const short8*)&Bl[wn + ni * 16 + lm][lk];
        }
        #pragma unroll
        for (int mi = 0; mi < 4; mi++) {
            #pragma unroll
            for (int ni = 0; ni < 4; ni++) {
                acc[mi][ni] = __builtin_amdgcn_mfma_f32_16x16x32_bf16(ah[mi], bh[ni], acc[mi][ni], 0, 0, 0);
                acc[mi][ni] = __builtin_amdgcn_mfma_f32_16x16x32_bf16(ah[mi], bl[ni], acc[mi][ni], 0, 0, 0);
                acc[mi][ni] = __builtin_amdgcn_mfma_f32_16x16x32_bf16(al[mi], bh[ni], acc[mi][ni], 0, 0, 0);
            }
        }
        __syncthreads();
    }

    const int crow = wm + ((lane >> 4) * 4);
    const int ccol = wn + (lane & 15);
    #pragma unroll
    for (int ni = 0; ni < 4; ni++) {
        const int col = n0 + ccol + ni * 16;
        const float bias = bih[col];
        #pragma unroll
        for (int mi = 0; mi < 4; mi++) {
            #pragma unroll
            for (int i = 0; i < 4; i++) {
                const size_t row = (size_t)(m0 + crow + mi * 16 + i);
                const float val = acc[mi][ni][i] + bias;
                if (BF16OUT) ((unsigned short*)xg_out)[row * NG + col] = f2bf(val);
                else         ((float*)xg_out)[row * NG + col] = val;
            }
        }
    }
}

// ---------- Kernel B: MFMA recurrence, 4 batch rows / block, 64 blocks ----------
// 512 threads = 8 waves (2/SIMD). Wave wv owns hidden cols [16wv,16wv+16) for
// all 3 gates (N-tiles wv, 8+wv, 16+wv); B = W_hh^T persistent in VGPRs as
// hi+lo split (exact); A = 4 h rows (bf16, LDS, double-buffered; rows 4..15
// zero -> M-waste but MFMA count is independent of M fill). 24 MFMAs/wave/step
// = 48/SIMD ~ 820 cyc. xg prefetch issued at TOP of step (address-only dep)
// so the MFMA phase hides its latency; consumed next step. Activation +
// h-writeback on quad-0 lanes (D rows 0..3 live there). One raw
// lgkmcnt-only barrier per step (vmcnt stays in flight).
template <bool BF16XG>
__launch_bounds__(512, 2)
__global__ void gru_mfma(const void* __restrict__ xg_in,
                         const float* __restrict__ Whh,
                         const float* __restrict__ bhh,
                         float* __restrict__ hstate,
                         int t0, int CT, int initial, int final_chunk,
                         const float* __restrict__ Wout,
                         const float* __restrict__ bout,
                         float* __restrict__ out)
{
    const int tid  = threadIdx.x;
    const int wv   = tid >> 6;      // 0..7
    const int lane = tid & 63;
    const int lm   = lane & 15;
    const int quad = lane >> 4;
    const int R0   = blockIdx.x * RPB;   // this block's batch rows
    const int j    = wv * 16 + lm;       // this lane's hidden column (0..127)

    __shared__ alignas(16) unsigned short h_s[2][16][136];  // bf16 h (rows 0..3 live)
    __shared__ alignas(16) float hf[RPB][132];              // final h (head)

    // ---- zero both h buffers (rows 4..15 stay zero forever) ----
    for (int idx = tid; idx < 2 * 16 * 136; idx += 512)
        ((unsigned short*)h_s)[idx] = 0;

    // ---- persistent B fragments: B[k=kt*32+quad*8+i][n=lm] = Whh[t*128+j][k] ----
    short8 w_hi[3][4], w_lo[3][4];
    #pragma unroll
    for (int t = 0; t < 3; t++) {
        const float* wr = Whh + (size_t)(t * HID + j) * HID + quad * 8;
        #pragma unroll
        for (int kt = 0; kt < 4; kt++) {
            float4 f0 = *(const float4*)(wr + kt * 32);
            float4 f1 = *(const float4*)(wr + kt * 32 + 4);
            float vv[8] = {f0.x, f0.y, f0.z, f0.w, f1.x, f1.y, f1.z, f1.w};
            short8 h8, l8;
            #pragma unroll
            for (int i = 0; i < 8; i++) {
                unsigned short h = f2bf(vv[i]);
                h8[i] = (short)h;
                l8[i] = (short)f2bf(vv[i] - bf2f(h));
            }
            w_hi[t][kt] = h8;
            w_lo[t][kt] = l8;
        }
    }

    const float bhr = bhh[j], bhz = bhh[HID + j], bhn = bhh[2 * HID + j];

    const float* xgf = (const float*)xg_in;
    const unsigned short* xgb = (const unsigned short*)xg_in;

    // ---- per-lane h state + step-0 xg (quad-0 lanes own rows 0..3, col j) ----
    float hp[RPB] = {};
    float cxr[RPB] = {}, cxz[RPB] = {}, cxn[RPB] = {};
    if (quad == 0) {
        #pragma unroll
        for (int i = 0; i < RPB; i++) {
            hp[i] = initial ? 0.f : hstate[(size_t)(R0 + i) * HID + j];
            h_s[0][i][j] = f2bf(hp[i]);
            const size_t nb = ((size_t)(R0 + i) * CT) * NG + j;
            if (BF16XG) { cxr[i] = bf2f(xgb[nb]); cxz[i] = bf2f(xgb[nb + HID]); cxn[i] = bf2f(xgb[nb + 2 * HID]); }
            else        { cxr[i] = xgf[nb];       cxz[i] = xgf[nb + HID];       cxn[i] = xgf[nb + 2 * HID]; }
        }
    }
    __syncthreads();

    for (int tt = 0; tt < CT; tt++) {
        const int p = tt & 1;

        // ---- prefetch next step's xg FIRST (hidden under MFMA phase) ----
        float nxr[RPB], nxz[RPB], nxn[RPB];
        if (quad == 0 && tt + 1 < CT) {
            #pragma unroll
            for (int i = 0; i < RPB; i++) {
                const size_t nb = ((size_t)(R0 + i) * CT + tt + 1) * NG + j;
                if (BF16XG) { nxr[i] = bf2f(xgb[nb]); nxz[i] = bf2f(xgb[nb + HID]); nxn[i] = bf2f(xgb[nb + 2 * HID]); }
                else        { nxr[i] = xgf[nb];       nxz[i] = xgf[nb + HID];       nxn[i] = xgf[nb + 2 * HID]; }
            }
        }

        // ---- A fragments: A[m=lm][k=kt*32+quad*8+i] ----
        short8 a[4];
        #pragma unroll
        for (int kt = 0; kt < 4; kt++)
            a[kt] = *(const short8*)&h_s[p][lm][kt * 32 + quad * 8];

        // ---- hg tiles: (W_hi + W_lo) x h_bf16 ----
        f32x4 acc[3] = {};
        #pragma unroll
        for (int kt = 0; kt < 4; kt++) {
            #pragma unroll
            for (int t = 0; t < 3; t++)
                acc[t] = __builtin_amdgcn_mfma_f32_16x16x32_bf16(a[kt], w_hi[t][kt], acc[t], 0, 0, 0);
            #pragma unroll
            for (int t = 0; t < 3; t++)
                acc[t] = __builtin_amdgcn_mfma_f32_16x16x32_bf16(a[kt], w_lo[t][kt], acc[t], 0, 0, 0);
        }

        // ---- activation on quad-0 lanes (D row = quad*4+reg -> rows 0..3) ----
        if (quad == 0) {
            #pragma unroll
            for (int i = 0; i < RPB; i++) {
                float rg = 1.f / (1.f + __expf(-(cxr[i] + acc[0][i] + bhr)));
                float zg = 1.f / (1.f + __expf(-(cxz[i] + acc[1][i] + bhz)));
                float nv = cxn[i] + rg * (acc[2][i] + bhn);
                float e  = __expf(2.f * nv);
                float ng = 1.f - 2.f / (e + 1.f);   // tanh, saturates at +/-inf
                hp[i] = (1.f - zg) * ng + zg * hp[i];
                h_s[1 - p][i][j] = f2bf(hp[i]);
            }
            if (tt + 1 < CT) {
                #pragma unroll
                for (int i = 0; i < RPB; i++) { cxr[i] = nxr[i]; cxz[i] = nxz[i]; cxn[i] = nxn[i]; }
            }
        }
        // drain LDS only (vmcnt prefetch stays in flight), then barrier
        asm volatile("s_waitcnt lgkmcnt(0)\ns_barrier" ::: "memory");
    }

    if (!final_chunk) {
        if (quad == 0) {
            #pragma unroll
            for (int i = 0; i < RPB; i++)
                hstate[(size_t)(R0 + i) * HID + j] = hp[i];
        }
        return;
    }

    // ---- head: relu -> 2-class linear -> log_softmax ----
    if (quad == 0) {
        #pragma unroll
        for (int i = 0; i < RPB; i++)
            hf[i][j] = hp[i];
    }
    __syncthreads();

    if (wv < RPB) {   // wave wv reduces batch row R0+wv
        const int row = wv;
        float f0 = hf[row][lane];       f0 = f0 > 0.f ? f0 : 0.f;
        float f1 = hf[row][lane + 64];  f1 = f1 > 0.f ? f1 : 0.f;
        float l0 = f0 * Wout[lane] + f1 * Wout[lane + 64];
        float l1 = f0 * Wout[HID + lane] + f1 * Wout[HID + lane + 64];
        #pragma unroll
        for (int d = 32; d > 0; d >>= 1) {
            l0 += __shfl_down(l0, d, 64);
            l1 += __shfl_down(l1, d, 64);
        }
        if (lane == 0) {
            l0 += bout[0]; l1 += bout[1];
            float m = fmaxf(l0, l1);
            float lse = m + logf(__expf(l0 - m) + __expf(l1 - m));
            out[(R0 + row) * 2 + 0] = l0 - lse;
            out[(R0 + row) * 2 + 1] = l1 - lse;
        }
    }
}

// ---------- launch ----------
extern "C" void kernel_launch(void* const* d_in, const int* in_sizes, int n_in,
                              void* d_out, int out_size, void* d_ws, size_t ws_size,
                              hipStream_t stream) {
    const float* x    = (const float*)d_in[0];
    const float* Wih  = (const float*)d_in[1];
    const float* Whh  = (const float*)d_in[2];
    const float* bih  = (const float*)d_in[3];
    const float* bhh  = (const float*)d_in[4];
    const float* Wout = (const float*)d_in[5];
    const float* bout = (const float*)d_in[6];
    float* out = (float*)d_out;

    // ws layout: [W_hi | W_lo | hstate | xg]
    unsigned short* Whi = (unsigned short*)d_ws;                       // 384*320*2 = 245760 B
    unsigned short* Wlo = (unsigned short*)((char*)d_ws + 245760);
    float* hstate = (float*)((char*)d_ws + 491520);                    // 128 KiB
    void*  xg     = (void*)((char*)d_ws + 622592);
    const size_t avail = ws_size > 622592 ? ws_size - 622592 : 0;

    bool bf16;
    int CT;
    if (avail >= (size_t)BATCH * SEQ * NG * 4) {        // fp32 xg (201 MB)
        bf16 = false; CT = SEQ;
    } else if (avail >= (size_t)BATCH * SEQ * NG * 2) { // bf16 xg (100 MB)
        bf16 = true;  CT = SEQ;
    } else {                                            // chunked bf16
        bf16 = true;
        CT = 64;
        while (CT * 2 <= SEQ && avail >= (size_t)BATCH * (size_t)(CT * 2) * NG * 2) CT *= 2;
    }

    conv_wih<<<(NG * KP + 255) / 256, 256, 0, stream>>>(Wih, Whi, Wlo);

    for (int t0 = 0; t0 < SEQ; t0 += CT) {
        dim3 gridA(NG / 128, (BATCH * CT) / 128);
        const int initial = (t0 == 0);
        const int final_chunk = (t0 + CT >= SEQ);
        if (bf16) {
            xg_mfma<true><<<gridA, 256, 0, stream>>>(x, Whi, Wlo, bih, xg, t0, CT);
            gru_mfma<true><<<BATCH / RPB, 512, 0, stream>>>(xg, Whh, bhh, hstate, t0, CT,
                                                            initial, final_chunk, Wout, bout, out);
        } else {
            xg_mfma<false><<<gridA, 256, 0, stream>>>(x, Whi, Wlo, bih, xg, t0, CT);
            gru_mfma<false><<<BATCH / RPB, 512, 0, stream>>>(xg, Whh, bhh, hstate, t0, CT,
                                                             initial, final_chunk, Wout, bout, out);
        }
    }
}

// Round 8
// 1124.459 us; speedup vs baseline: 1.2370x; 1.0068x over previous
//
#include <hip/hip_runtime.h>
#include <hip/hip_bf16.h>
#include <math.h>

#define BATCH 256
#define SEQ   512
#define INS   300
#define KP    320   // K padded to 10 x 32 (xg gemm)
#define HID   128
#define NG    384   // 3*HID
#define RPB   4     // batch rows per gru block

typedef __attribute__((ext_vector_type(8))) short short8;   // 8 x bf16 (4 VGPRs)
typedef __attribute__((ext_vector_type(4))) float f32x4;

// ---------- helpers ----------
__device__ __forceinline__ float bf2f(unsigned short u) {
    unsigned int v = ((unsigned int)u) << 16;
    return __uint_as_float(v);
}
__device__ __forceinline__ unsigned short f2bf(float f) {
    unsigned int u = __float_as_uint(f);
    unsigned int r = (u + 0x7FFFu + ((u >> 16) & 1u)) >> 16;
    return (unsigned short)r;
}
// Pin a 128-bit fragment in VGPRs: the asm becomes the value's definer, so the
// compiler cannot rematerialize its construction inside the K-loop (R7 bug:
// VALUBusy 58%/active-CU from re-building W fragments every step).
__device__ __forceinline__ short8 pin8(short8 x) {
    union { short8 s; unsigned int u[4]; } t;
    t.s = x;
    asm volatile("" : "+v"(t.u[0]), "+v"(t.u[1]), "+v"(t.u[2]), "+v"(t.u[3]));
    return t.s;
}

// ---------- Kernel 0: split W_ih (fp32 384x300) -> bf16 hi/lo planes (384x320, k-padded) ----------
__global__ void conv_wih(const float* __restrict__ Wih,
                         unsigned short* __restrict__ Whi,
                         unsigned short* __restrict__ Wlo)
{
    int idx = blockIdx.x * 256 + threadIdx.x;     // 0 .. 384*320-1
    if (idx >= NG * KP) return;
    int g = idx / KP, k = idx - g * KP;
    float v = (k < INS) ? Wih[g * INS + k] : 0.f;
    unsigned short h = f2bf(v);
    float r = v - bf2f(h);
    Whi[idx] = h;
    Wlo[idx] = f2bf(r);
}

// ---------- Kernel A: xg = x @ W_ih^T + b_ih via split-bf16 MFMA (unchanged) ----------
template <bool BF16OUT>
__launch_bounds__(256)
__global__ void xg_mfma(const float* __restrict__ x,
                        const unsigned short* __restrict__ Whi,
                        const unsigned short* __restrict__ Wlo,
                        const float* __restrict__ bih,
                        void* __restrict__ xg_out,
                        int t0, int CT)
{
    __shared__ unsigned short Ah[128][40], Al[128][40];
    __shared__ unsigned short Bh[128][40], Bl[128][40];

    const int tid  = threadIdx.x;
    const int lane = tid & 63;
    const int w    = tid >> 6;
    const int wm   = (w & 1) * 64;
    const int wn   = (w >> 1) * 64;
    const int n0   = blockIdx.x * 128;
    const int m0   = blockIdx.y * 128;

    const int srow = tid >> 1;
    const int shalf = tid & 1;
    const int rr = m0 + srow;
    const int bb = rr / CT;
    const float* xrow = x + (size_t)(bb * SEQ + t0 + (rr - bb * CT)) * INS;

    f32x4 acc[4][4] = {};

    for (int ks = 0; ks < KP / 32; ks++) {
        const int k0 = ks * 32 + shalf * 16;
        float v[16];
        #pragma unroll
        for (int i = 0; i < 16; i += 4) {
            if (k0 + i + 4 <= INS) {
                float4 f = *(const float4*)(xrow + k0 + i);
                v[i] = f.x; v[i + 1] = f.y; v[i + 2] = f.z; v[i + 3] = f.w;
            } else {
                #pragma unroll
                for (int j = 0; j < 4; j++)
                    v[i + j] = (k0 + i + j < INS) ? xrow[k0 + i + j] : 0.f;
            }
        }
        union { unsigned short us[8]; uint4 q; } ph, pl;
        #pragma unroll
        for (int gblk = 0; gblk < 2; gblk++) {
            #pragma unroll
            for (int i = 0; i < 8; i++) {
                float f = v[gblk * 8 + i];
                unsigned short h = f2bf(f);
                ph.us[i] = h;
                pl.us[i] = f2bf(f - bf2f(h));
            }
            *(uint4*)&Ah[srow][shalf * 16 + gblk * 8] = ph.q;
            *(uint4*)&Al[srow][shalf * 16 + gblk * 8] = pl.q;
        }
        {
            const size_t off = (size_t)(n0 + srow) * KP + ks * 32 + shalf * 16;
            const uint4* sh = (const uint4*)(Whi + off);
            const uint4* sl = (const uint4*)(Wlo + off);
            *(uint4*)&Bh[srow][shalf * 16]     = sh[0];
            *(uint4*)&Bh[srow][shalf * 16 + 8] = sh[1];
            *(uint4*)&Bl[srow][shalf * 16]     = sl[0];
            *(uint4*)&Bl[srow][shalf * 16 + 8] = sl[1];
        }
        __syncthreads();

        const int lm = lane & 15;
        const int lk = (lane >> 4) * 8;
        short8 ah[4], al[4], bh[4], bl[4];
        #pragma unroll
        for (int mi = 0; mi < 4; mi++) {
            ah[mi] = *(const short8*)&Ah[wm + mi * 16 + lm][lk];
            al[mi] = *(const short8*)&Al[wm + mi * 16 + lm][lk];
        }
        #pragma unroll
        for (int ni = 0; ni < 4; ni++) {
            bh[ni] = *(const short8*)&Bh[wn + ni * 16 + lm][lk];
            bl[ni] = *(const short8*)&Bl[wn + ni * 16 + lm][lk];
        }
        #pragma unroll
        for (int mi = 0; mi < 4; mi++) {
            #pragma unroll
            for (int ni = 0; ni < 4; ni++) {
                acc[mi][ni] = __builtin_amdgcn_mfma_f32_16x16x32_bf16(ah[mi], bh[ni], acc[mi][ni], 0, 0, 0);
                acc[mi][ni] = __builtin_amdgcn_mfma_f32_16x16x32_bf16(ah[mi], bl[ni], acc[mi][ni], 0, 0, 0);
                acc[mi][ni] = __builtin_amdgcn_mfma_f32_16x16x32_bf16(al[mi], bh[ni], acc[mi][ni], 0, 0, 0);
            }
        }
        __syncthreads();
    }

    const int crow = wm + ((lane >> 4) * 4);
    const int ccol = wn + (lane & 15);
    #pragma unroll
    for (int ni = 0; ni < 4; ni++) {
        const int col = n0 + ccol + ni * 16;
        const float bias = bih[col];
        #pragma unroll
        for (int mi = 0; mi < 4; mi++) {
            #pragma unroll
            for (int i = 0; i < 4; i++) {
                const size_t row = (size_t)(m0 + crow + mi * 16 + i);
                const float val = acc[mi][ni][i] + bias;
                if (BF16OUT) ((unsigned short*)xg_out)[row * NG + col] = f2bf(val);
                else         ((float*)xg_out)[row * NG + col] = val;
            }
        }
    }
}

// ---------- Kernel B: MFMA recurrence, 4 batch rows / block, 64 blocks ----------
// Same structure as R7 but with W fragments PINNED in VGPRs (pin8) so the
// compiler cannot rematerialize their construction per step, and prefetch
// addressing reduced to 4 running pointers + immediate offsets.
template <bool BF16XG>
__launch_bounds__(512, 2)
__global__ void gru_mfma(const void* __restrict__ xg_in,
                         const float* __restrict__ Whh,
                         const float* __restrict__ bhh,
                         float* __restrict__ hstate,
                         int t0, int CT, int initial, int final_chunk,
                         const float* __restrict__ Wout,
                         const float* __restrict__ bout,
                         float* __restrict__ out)
{
    const int tid  = threadIdx.x;
    const int wv   = tid >> 6;      // 0..7
    const int lane = tid & 63;
    const int lm   = lane & 15;
    const int quad = lane >> 4;
    const int R0   = blockIdx.x * RPB;   // this block's batch rows
    const int j    = wv * 16 + lm;       // this lane's hidden column (0..127)

    __shared__ alignas(16) unsigned short h_s[2][16][136];  // bf16 h (rows 0..3 live)
    __shared__ alignas(16) float hf[RPB][132];              // final h (head)

    // ---- zero both h buffers (rows 4..15 stay zero forever) ----
    for (int idx = tid; idx < 2 * 16 * 136; idx += 512)
        ((unsigned short*)h_s)[idx] = 0;

    // ---- persistent B fragments: B[k=kt*32+quad*8+i][n=lm] = Whh[t*128+j][k] ----
    short8 w_hi[3][4], w_lo[3][4];
    #pragma unroll
    for (int t = 0; t < 3; t++) {
        const float* wr = Whh + (size_t)(t * HID + j) * HID + quad * 8;
        #pragma unroll
        for (int kt = 0; kt < 4; kt++) {
            float4 f0 = *(const float4*)(wr + kt * 32);
            float4 f1 = *(const float4*)(wr + kt * 32 + 4);
            float vv[8] = {f0.x, f0.y, f0.z, f0.w, f1.x, f1.y, f1.z, f1.w};
            short8 h8, l8;
            #pragma unroll
            for (int i = 0; i < 8; i++) {
                unsigned short h = f2bf(vv[i]);
                h8[i] = (short)h;
                l8[i] = (short)f2bf(vv[i] - bf2f(h));
            }
            w_hi[t][kt] = pin8(h8);   // asm-defined: cannot be rematerialized
            w_lo[t][kt] = pin8(l8);
        }
    }

    const float bhr = bhh[j], bhz = bhh[HID + j], bhn = bhh[2 * HID + j];

    // ---- running xg pointers (quad-0 lanes): row R0+i, col j; +HID/+2HID via imm offset ----
    const unsigned short* pxb[RPB];
    const float*          pxf[RPB];
    #pragma unroll
    for (int i = 0; i < RPB; i++) {
        const size_t nb = ((size_t)(R0 + i) * CT) * NG + j;
        pxb[i] = (const unsigned short*)xg_in + nb;
        pxf[i] = (const float*)xg_in + nb;
    }

    // ---- per-lane h state + step-0 xg ----
    float hp[RPB] = {};
    float cxr[RPB] = {}, cxz[RPB] = {}, cxn[RPB] = {};
    if (quad == 0) {
        #pragma unroll
        for (int i = 0; i < RPB; i++) {
            hp[i] = initial ? 0.f : hstate[(size_t)(R0 + i) * HID + j];
            h_s[0][i][j] = f2bf(hp[i]);
            if (BF16XG) { cxr[i] = bf2f(pxb[i][0]); cxz[i] = bf2f(pxb[i][HID]); cxn[i] = bf2f(pxb[i][2 * HID]); }
            else        { cxr[i] = pxf[i][0];       cxz[i] = pxf[i][HID];       cxn[i] = pxf[i][2 * HID]; }
        }
    }
    __syncthreads();

    for (int tt = 0; tt < CT; tt++) {
        const int p = tt & 1;

        // ---- prefetch next step's xg FIRST (hidden under MFMA phase) ----
        float nxr[RPB], nxz[RPB], nxn[RPB];
        if (quad == 0 && tt + 1 < CT) {
            #pragma unroll
            for (int i = 0; i < RPB; i++) {
                if (BF16XG) { nxr[i] = bf2f(pxb[i][NG]); nxz[i] = bf2f(pxb[i][NG + HID]); nxn[i] = bf2f(pxb[i][NG + 2 * HID]); }
                else        { nxr[i] = pxf[i][NG];       nxz[i] = pxf[i][NG + HID];       nxn[i] = pxf[i][NG + 2 * HID]; }
            }
        }

        // ---- A fragments: A[m=lm][k=kt*32+quad*8+i] ----
        short8 a[4];
        #pragma unroll
        for (int kt = 0; kt < 4; kt++)
            a[kt] = *(const short8*)&h_s[p][lm][kt * 32 + quad * 8];

        // ---- hg tiles: (W_hi + W_lo) x h_bf16 ----
        f32x4 acc[3] = {};
        #pragma unroll
        for (int kt = 0; kt < 4; kt++) {
            #pragma unroll
            for (int t = 0; t < 3; t++)
                acc[t] = __builtin_amdgcn_mfma_f32_16x16x32_bf16(a[kt], w_hi[t][kt], acc[t], 0, 0, 0);
            #pragma unroll
            for (int t = 0; t < 3; t++)
                acc[t] = __builtin_amdgcn_mfma_f32_16x16x32_bf16(a[kt], w_lo[t][kt], acc[t], 0, 0, 0);
        }

        // ---- activation on quad-0 lanes (D row = quad*4+reg -> rows 0..3) ----
        if (quad == 0) {
            #pragma unroll
            for (int i = 0; i < RPB; i++) {
                float rg = 1.f / (1.f + __expf(-(cxr[i] + acc[0][i] + bhr)));
                float zg = 1.f / (1.f + __expf(-(cxz[i] + acc[1][i] + bhz)));
                float nv = cxn[i] + rg * (acc[2][i] + bhn);
                float e  = __expf(2.f * nv);
                float ng = 1.f - 2.f / (e + 1.f);   // tanh, saturates at +/-inf
                hp[i] = (1.f - zg) * ng + zg * hp[i];
                h_s[1 - p][i][j] = f2bf(hp[i]);
            }
            if (tt + 1 < CT) {
                #pragma unroll
                for (int i = 0; i < RPB; i++) { cxr[i] = nxr[i]; cxz[i] = nxz[i]; cxn[i] = nxn[i]; }
            }
        }
        // advance pointers (uniform, cheap), drain LDS only, barrier
        #pragma unroll
        for (int i = 0; i < RPB; i++) { pxb[i] += NG; pxf[i] += NG; }
        asm volatile("s_waitcnt lgkmcnt(0)\ns_barrier" ::: "memory");
    }

    if (!final_chunk) {
        if (quad == 0) {
            #pragma unroll
            for (int i = 0; i < RPB; i++)
                hstate[(size_t)(R0 + i) * HID + j] = hp[i];
        }
        return;
    }

    // ---- head: relu -> 2-class linear -> log_softmax ----
    if (quad == 0) {
        #pragma unroll
        for (int i = 0; i < RPB; i++)
            hf[i][j] = hp[i];
    }
    __syncthreads();

    if (wv < RPB) {   // wave wv reduces batch row R0+wv
        const int row = wv;
        float f0 = hf[row][lane];       f0 = f0 > 0.f ? f0 : 0.f;
        float f1 = hf[row][lane + 64];  f1 = f1 > 0.f ? f1 : 0.f;
        float l0 = f0 * Wout[lane] + f1 * Wout[lane + 64];
        float l1 = f0 * Wout[HID + lane] + f1 * Wout[HID + lane + 64];
        #pragma unroll
        for (int d = 32; d > 0; d >>= 1) {
            l0 += __shfl_down(l0, d, 64);
            l1 += __shfl_down(l1, d, 64);
        }
        if (lane == 0) {
            l0 += bout[0]; l1 += bout[1];
            float m = fmaxf(l0, l1);
            float lse = m + logf(__expf(l0 - m) + __expf(l1 - m));
            out[(R0 + row) * 2 + 0] = l0 - lse;
            out[(R0 + row) * 2 + 1] = l1 - lse;
        }
    }
}

// ---------- launch ----------
extern "C" void kernel_launch(void* const* d_in, const int* in_sizes, int n_in,
                              void* d_out, int out_size, void* d_ws, size_t ws_size,
                              hipStream_t stream) {
    const float* x    = (const float*)d_in[0];
    const float* Wih  = (const float*)d_in[1];
    const float* Whh  = (const float*)d_in[2];
    const float* bih  = (const float*)d_in[3];
    const float* bhh  = (const float*)d_in[4];
    const float* Wout = (const float*)d_in[5];
    const float* bout = (const float*)d_in[6];
    float* out = (float*)d_out;

    // ws layout: [W_hi | W_lo | hstate | xg]
    unsigned short* Whi = (unsigned short*)d_ws;                       // 384*320*2 = 245760 B
    unsigned short* Wlo = (unsigned short*)((char*)d_ws + 245760);
    float* hstate = (float*)((char*)d_ws + 491520);                    // 128 KiB
    void*  xg     = (void*)((char*)d_ws + 622592);
    const size_t avail = ws_size > 622592 ? ws_size - 622592 : 0;

    bool bf16;
    int CT;
    if (avail >= (size_t)BATCH * SEQ * NG * 4) {        // fp32 xg (201 MB)
        bf16 = false; CT = SEQ;
    } else if (avail >= (size_t)BATCH * SEQ * NG * 2) { // bf16 xg (100 MB)
        bf16 = true;  CT = SEQ;
    } else {                                            // chunked bf16
        bf16 = true;
        CT = 64;
        while (CT * 2 <= SEQ && avail >= (size_t)BATCH * (size_t)(CT * 2) * NG * 2) CT *= 2;
    }

    conv_wih<<<(NG * KP + 255) / 256, 256, 0, stream>>>(Wih, Whi, Wlo);

    for (int t0 = 0; t0 < SEQ; t0 += CT) {
        dim3 gridA(NG / 128, (BATCH * CT) / 128);
        const int initial = (t0 == 0);
        const int final_chunk = (t0 + CT >= SEQ);
        if (bf16) {
            xg_mfma<true><<<gridA, 256, 0, stream>>>(x, Whi, Wlo, bih, xg, t0, CT);
            gru_mfma<true><<<BATCH / RPB, 512, 0, stream>>>(xg, Whh, bhh, hstate, t0, CT,
                                                            initial, final_chunk, Wout, bout, out);
        } else {
            xg_mfma<false><<<gridA, 256, 0, stream>>>(x, Whi, Wlo, bih, xg, t0, CT);
            gru_mfma<false><<<BATCH / RPB, 512, 0, stream>>>(xg, Whh, bhh, hstate, t0, CT,
                                                             initial, final_chunk, Wout, bout, out);
        }
    }
}